// Round 1
// baseline (1078.196 us; speedup 1.0000x reference)
//
#include <hip/hip_runtime.h>

#define SMALLV -1000.0f

constexpr int L    = 128;
constexpr int TDIM = 1024;
constexpr int NB   = 128;
constexpr int START = L - 2; // 126
constexpr int STOP  = L - 1; // 127

// One block per batch element. Thread j owns column j of E = exp(transitions).
// State carried in scaled linear space: alpha[j] = log(u[j]) + C, with u
// renormalized by its max every step (exact, via wave butterfly max).
__global__ __launch_bounds__(128, 1)
void crf_forward(const float* __restrict__ pred,
                 const float* __restrict__ trans,
                 const int* __restrict__ seq_len,
                 float* __restrict__ fwd_out)
{
    const int b = blockIdx.x;
    const int j = threadIdx.x;
    const int sl = seq_len[b];

    // E[i] = exp(trans[i][j]) — column j, kept entirely in VGPRs (static idx).
    float E[L];
#pragma unroll
    for (int i = 0; i < L; ++i) {
        E[i] = __expf(trans[i * L + j]);
    }

    __shared__ float wbuf[2][L];
    __shared__ float wmax[2][2];

    // u_0: 1 at START, 0 elsewhere (exp(SMALL) == 0 in fp32). m_0 = 1.
    wbuf[0][j] = (j == START) ? 1.0f : 0.0f;
    if (j == 0) { wmax[0][0] = 1.0f; wmax[0][1] = 1.0f; }
    __syncthreads();

    const float* prow = pred + (long)b * TDIM * L + j;
    // emit prefetch, depth 2
    float e0 = prow[0];
    float e1 = (sl >= 2) ? prow[L] : 0.0f;

    float C = 0.0f;
    int buf = 0;
    const bool dead = (j == START) || (j == STOP);

    for (int t = 1; t <= sl; ++t) {
        // prefetch emit row t+1 (consumed at step t+2)
        float epf = (t + 1 < sl) ? prow[(long)(t + 1) * L] : 0.0f;

        float m = fmaxf(wmax[buf][0], wmax[buf][1]);
        C += __logf(m);
        float inv_m = 1.0f / m;

        const float* wb = wbuf[buf];
        float a0 = 0.f, a1 = 0.f, a2 = 0.f, a3 = 0.f;
#pragma unroll
        for (int i = 0; i < L; i += 4) {
            float4 w4 = *(const float4*)(wb + i);   // broadcast ds_read_b128
            a0 = fmaf(w4.x, E[i + 0], a0);
            a1 = fmaf(w4.y, E[i + 1], a1);
            a2 = fmaf(w4.z, E[i + 2], a2);
            a3 = fmaf(w4.w, E[i + 3], a3);
        }
        float acc = (a0 + a1) + (a2 + a3);

        float p = dead ? 0.0f : __expf(e0);
        float u = acc * inv_m * p;

        wbuf[buf ^ 1][j] = u;
        float wm = u;
#pragma unroll
        for (int d = 1; d < 64; d <<= 1) wm = fmaxf(wm, __shfl_xor(wm, d));
        if ((j & 63) == 0) wmax[buf ^ 1][j >> 6] = wm;
        __syncthreads();
        buf ^= 1;
        e0 = e1;
        e1 = epf;
    }

    // Final STOP step: emit = SMALL except STOP=0, so only column STOP survives.
    float m = fmaxf(wmax[buf][0], wmax[buf][1]);
    C += __logf(m);
    float inv_m = 1.0f / m;
    const float* wb = wbuf[buf];
    float a0 = 0.f, a1 = 0.f, a2 = 0.f, a3 = 0.f;
#pragma unroll
    for (int i = 0; i < L; i += 4) {
        float4 w4 = *(const float4*)(wb + i);
        a0 = fmaf(w4.x, E[i + 0], a0);
        a1 = fmaf(w4.y, E[i + 1], a1);
        a2 = fmaf(w4.z, E[i + 2], a2);
        a3 = fmaf(w4.w, E[i + 3], a3);
    }
    float acc = (a0 + a1) + (a2 + a3);
    if (j == STOP) {
        fwd_out[b] = __logf(acc * inv_m) + C;
    }
}

// Gold path score per batch: emits at the tag + transition chain START->...->STOP.
__global__ __launch_bounds__(256)
void crf_score(const float* __restrict__ pred,
               const float* __restrict__ trans,
               const int* __restrict__ tags,
               const int* __restrict__ seq_len,
               float* __restrict__ score_out)
{
    const int b = blockIdx.x;
    const int tid = threadIdx.x;
    const int sl = seq_len[b];
    const int* tg = tags + b * TDIM;

    float s = 0.0f;
    for (int t = tid; t < sl; t += 256) {
        int tag = tg[t];
        s += pred[((long)b * TDIM + t) * L + tag];
        int prev = (t == 0) ? START : tg[t - 1];
        s += trans[prev * L + tag];
    }
    if (tid == 0) s += trans[tg[sl - 1] * L + STOP];

    __shared__ float red[4];
#pragma unroll
    for (int d = 1; d < 64; d <<= 1) s += __shfl_xor(s, d);
    if ((tid & 63) == 0) red[tid >> 6] = s;
    __syncthreads();
    if (tid == 0) score_out[b] = (red[0] + red[1]) + (red[2] + red[3]);
}

__global__ __launch_bounds__(128)
void crf_combine(const float* __restrict__ fwd,
                 const float* __restrict__ real,
                 float* __restrict__ out)
{
    const int tid = threadIdx.x; // 128
    float s = fwd[tid] - real[tid];
#pragma unroll
    for (int d = 1; d < 64; d <<= 1) s += __shfl_xor(s, d);
    __shared__ float red[2];
    if ((tid & 63) == 0) red[tid >> 6] = s;
    __syncthreads();
    if (tid == 0) out[0] = red[0] + red[1];
}

extern "C" void kernel_launch(void* const* d_in, const int* in_sizes, int n_in,
                              void* d_out, int out_size, void* d_ws, size_t ws_size,
                              hipStream_t stream)
{
    const float* pred    = (const float*)d_in[0];
    const float* trans   = (const float*)d_in[1];
    const int*   tags    = (const int*)d_in[2];
    const int*   seq_len = (const int*)d_in[3];

    float* ws   = (float*)d_ws;
    float* fwd  = ws;        // 128 floats
    float* real = ws + 128;  // 128 floats

    crf_forward<<<NB, 128, 0, stream>>>(pred, trans, seq_len, fwd);
    crf_score  <<<NB, 256, 0, stream>>>(pred, trans, tags, seq_len, real);
    crf_combine<<<1, 128, 0, stream>>>(fwd, real, (float*)d_out);
}

// Round 2
// 638.275 us; speedup vs baseline: 1.6892x; 1.6892x over previous
//
#include <hip/hip_runtime.h>

constexpr int L     = 128;
constexpr int TDIM  = 1024;
constexpr int NBATCH = 128;
constexpr int START = L - 2; // 126
constexpr int STOP  = L - 1; // 127
constexpr int BSUB  = 16;            // batches (M rows) per block
constexpr int NBLK  = NBATCH / BSUB; // 8

typedef short bf16x8 __attribute__((ext_vector_type(8)));
typedef float f32x4  __attribute__((ext_vector_type(4)));

__device__ __forceinline__ short f2bf(float f) {
    unsigned x = __float_as_uint(f);
    unsigned r = (x + 0x7fffu + ((x >> 16) & 1u)) >> 16; // RNE
    return (short)r;
}

// One block per 16 batches. State U (16x128, bf16) lives in swizzled LDS,
// double-buffered. E = exp(trans) lives in VGPRs as MFMA B-fragments.
// Per step: U_new = (U @ E) * P_t, with trigger-based 2^-64 renorm folded
// into P. Answer for batch b extracted from the STOP column of D = U@E at
// t == seq_len[b]+1 (before applying P), then the row is zeroed via P.
__global__ __launch_bounds__(256, 1)
void crf_forward_mfma(const float* __restrict__ pred,
                      const float* __restrict__ trans,
                      const int* __restrict__ seq_len,
                      float* __restrict__ fwd_out)
{
    const int tid  = threadIdx.x;
    const int wave = tid >> 6;
    const int lane = tid & 63;
    const int l15  = lane & 15;
    const int l4   = lane >> 4;
    const int bbase = blockIdx.x * BSUB;
    const int row0  = l4 * 4;        // C/D rows this lane holds (row0..row0+3)
    const int c0 = wave * 32 + l15;  // N columns this lane touches
    const int c1 = c0 + 16;

    // --- B-fragments: E[k][c] = exp(trans[k][c]), cols [wave*32, wave*32+32)
    // layout: lane l, elem e -> B[(l>>4)*8 + e + 32*kt][l&15 + ntBase]
    bf16x8 Bf0[4], Bf1[4];
#pragma unroll
    for (int kt = 0; kt < 4; ++kt) {
        bf16x8 v0, v1;
#pragma unroll
        for (int e = 0; e < 8; ++e) {
            int k = kt * 32 + l4 * 8 + e;
            v0[e] = f2bf(__expf(trans[k * L + c0]));
            v1[e] = f2bf(__expf(trans[k * L + c1]));
        }
        Bf0[kt] = v0; Bf1[kt] = v1;
    }

    __shared__ short ubuf[2][BSUB * L]; // bf16, XOR-swizzled rows
    __shared__ int   flags[2][4];       // step-stamped renorm triggers per wave

    // u0: 1.0 at START column, else 0  (exp of start_state)
    for (int idx = tid; idx < BSUB * L; idx += 256) {
        int row = idx >> 7, col = idx & (L - 1);
        int byte = row * 256 + ((col * 2) ^ ((row & 7) << 4));
        ubuf[0][byte >> 1] = f2bf(col == START ? 1.0f : 0.0f);
    }
    if (lane == 0) { flags[0][wave] = 0; flags[1][wave] = 0; }

    int srow[4];
#pragma unroll
    for (int r = 0; r < 4; ++r) srow[r] = seq_len[bbase + row0 + r];
    int tmax = 1;
    for (int i = 0; i < BSUB; ++i) tmax = max(tmax, seq_len[bbase + i]);
    tmax += 1;

    const float* rp[4];
#pragma unroll
    for (int r = 0; r < 4; ++r)
        rp[r] = pred + (long)(bbase + row0 + r) * TDIM * L;

    // emit prefetch for t=1 (pred row 0)
    float er0[4], er1[4];
#pragma unroll
    for (int r = 0; r < 4; ++r) { er0[r] = rp[r][c0]; er1[r] = rp[r][c1]; }

    float C = 0.0f;       // global log-offset (uniform across block)
    float scale = 1.0f;   // 2^-64 when renorm pending (applied via P)
    float cadd  = 0.0f;   // matching C increment, added after extraction

    __syncthreads();

    for (int t = 1; t <= tmax; ++t) {
        const int cur = (t - 1) & 1, nxt = t & 1;

        // A-fragments: A[row=l&15][k = (l>>4)*8+e + 32*kt] from swizzled LDS
        bf16x8 A0, A1, A2, A3;
        {
            const char* ub = (const char*)(&ubuf[cur][0]);
            const int swz  = (l15 & 7) << 4;
            const int base = l15 * 256;
            A0 = *(const bf16x8*)(ub + base + ((l4 * 16 +   0) ^ swz));
            A1 = *(const bf16x8*)(ub + base + ((l4 * 16 +  64) ^ swz));
            A2 = *(const bf16x8*)(ub + base + ((l4 * 16 + 128) ^ swz));
            A3 = *(const bf16x8*)(ub + base + ((l4 * 16 + 192) ^ swz));
        }

        // P for this step (emission row t-1), with renorm scale folded in.
        // Dead rows (t > sl) and START/STOP columns get 0.
        float p0[4], p1[4];
#pragma unroll
        for (int r = 0; r < 4; ++r) {
            bool live = (t <= srow[r]);
            float q0 = __expf(er0[r]) * scale;
            float q1 = __expf(er1[r]) * scale;
            p0[r] = live ? q0 : 0.0f;                                  // c0 <= 111 < START
            p1[r] = (live && c1 != START && c1 != STOP) ? q1 : 0.0f;
        }

        // prefetch emits for t+1 (pred row t, clamped in-bounds; dead rows ignore it)
        const long off = (long)min(t, TDIM - 1) * L;
        float en0[4], en1[4];
#pragma unroll
        for (int r = 0; r < 4; ++r) { en0[r] = rp[r][off + c0]; en1[r] = rp[r][off + c1]; }

        // D = U @ E   (two 16x16 N-tiles per wave, K=128 as 4 chained MFMAs)
        f32x4 acc0 = {0.f, 0.f, 0.f, 0.f};
        f32x4 acc1 = {0.f, 0.f, 0.f, 0.f};
        acc0 = __builtin_amdgcn_mfma_f32_16x16x32_bf16(A0, Bf0[0], acc0, 0, 0, 0);
        acc1 = __builtin_amdgcn_mfma_f32_16x16x32_bf16(A0, Bf1[0], acc1, 0, 0, 0);
        acc0 = __builtin_amdgcn_mfma_f32_16x16x32_bf16(A1, Bf0[1], acc0, 0, 0, 0);
        acc1 = __builtin_amdgcn_mfma_f32_16x16x32_bf16(A1, Bf1[1], acc1, 0, 0, 0);
        acc0 = __builtin_amdgcn_mfma_f32_16x16x32_bf16(A2, Bf0[2], acc0, 0, 0, 0);
        acc1 = __builtin_amdgcn_mfma_f32_16x16x32_bf16(A2, Bf1[2], acc1, 0, 0, 0);
        acc0 = __builtin_amdgcn_mfma_f32_16x16x32_bf16(A3, Bf0[3], acc0, 0, 0, 0);
        acc1 = __builtin_amdgcn_mfma_f32_16x16x32_bf16(A3, Bf1[3], acc1, 0, 0, 0);

        // extraction: STOP column of D, before P, before this step's C increment
        if (c1 == STOP) {
#pragma unroll
            for (int r = 0; r < 4; ++r)
                if (t == srow[r] + 1)
                    fwd_out[bbase + row0 + r] = __logf(acc1[r]) + C;
        }
        C += cadd;

        // U_new = D * P -> bf16 -> swizzled LDS (next buffer); overflow trigger
        int trig = 0;
        char* ubw = (char*)(&ubuf[nxt][0]);
#pragma unroll
        for (int r = 0; r < 4; ++r) {
            float u0 = acc0[r] * p0[r];
            float u1 = acc1[r] * p1[r];
            trig |= (u0 > 0x1p80f) | (u1 > 0x1p80f);
            int rowb = (row0 + r) * 256;
            int sz   = ((row0 + r) & 7) << 4;
            *(short*)(ubw + rowb + ((c0 * 2) ^ sz)) = f2bf(u0);
            *(short*)(ubw + rowb + ((c1 * 2) ^ sz)) = f2bf(u1);
        }
        unsigned long long m = __ballot(trig);
        if (lane == 0 && m) flags[nxt][wave] = t;  // step-stamped: no clearing needed

        __syncthreads();

        int any = (flags[nxt][0] == t) | (flags[nxt][1] == t) |
                  (flags[nxt][2] == t) | (flags[nxt][3] == t);
        scale = any ? 0x1p-64f : 1.0f;
        cadd  = any ? 44.3614195558365f : 0.0f;

#pragma unroll
        for (int r = 0; r < 4; ++r) { er0[r] = en0[r]; er1[r] = en1[r]; }
    }
}

// Gold path score per batch (unchanged — verified exact).
__global__ __launch_bounds__(256)
void crf_score(const float* __restrict__ pred,
               const float* __restrict__ trans,
               const int* __restrict__ tags,
               const int* __restrict__ seq_len,
               float* __restrict__ score_out)
{
    const int b = blockIdx.x;
    const int tid = threadIdx.x;
    const int sl = seq_len[b];
    const int* tg = tags + b * TDIM;

    float s = 0.0f;
    for (int t = tid; t < sl; t += 256) {
        int tag = tg[t];
        s += pred[((long)b * TDIM + t) * L + tag];
        int prev = (t == 0) ? START : tg[t - 1];
        s += trans[prev * L + tag];
    }
    if (tid == 0) s += trans[tg[sl - 1] * L + STOP];

    __shared__ float red[4];
#pragma unroll
    for (int d = 1; d < 64; d <<= 1) s += __shfl_xor(s, d);
    if ((tid & 63) == 0) red[tid >> 6] = s;
    __syncthreads();
    if (tid == 0) score_out[b] = (red[0] + red[1]) + (red[2] + red[3]);
}

__global__ __launch_bounds__(128)
void crf_combine(const float* __restrict__ fwd,
                 const float* __restrict__ real,
                 float* __restrict__ out)
{
    const int tid = threadIdx.x; // 128
    float s = fwd[tid] - real[tid];
#pragma unroll
    for (int d = 1; d < 64; d <<= 1) s += __shfl_xor(s, d);
    __shared__ float red[2];
    if ((tid & 63) == 0) red[tid >> 6] = s;
    __syncthreads();
    if (tid == 0) out[0] = red[0] + red[1];
}

extern "C" void kernel_launch(void* const* d_in, const int* in_sizes, int n_in,
                              void* d_out, int out_size, void* d_ws, size_t ws_size,
                              hipStream_t stream)
{
    const float* pred    = (const float*)d_in[0];
    const float* trans   = (const float*)d_in[1];
    const int*   tags    = (const int*)d_in[2];
    const int*   seq_len = (const int*)d_in[3];

    float* ws   = (float*)d_ws;
    float* fwd  = ws;        // 128 floats
    float* real = ws + 128;  // 128 floats

    crf_forward_mfma<<<NBLK, 256, 0, stream>>>(pred, trans, seq_len, fwd);
    crf_score      <<<NBATCH, 256, 0, stream>>>(pred, trans, tags, seq_len, real);
    crf_combine    <<<1, 128, 0, stream>>>(fwd, real, (float*)d_out);
}

// Round 4
// 538.264 us; speedup vs baseline: 2.0031x; 1.1858x over previous
//
#include <hip/hip_runtime.h>

constexpr int L      = 128;
constexpr int TDIM   = 1024;
constexpr int NBATCH = 128;
constexpr int START  = L - 2; // 126
constexpr int STOP   = L - 1; // 127
constexpr int BSUB   = 16;    // batches per wave (one wave per block)
constexpr int NBLK   = NBATCH / BSUB; // 8

typedef short bf16x8 __attribute__((ext_vector_type(8)));
typedef float f32x4  __attribute__((ext_vector_type(4)));
typedef int   i32x4  __attribute__((ext_vector_type(4)));

union B4 { i32x4 i; bf16x8 v; };

__device__ __forceinline__ short f2bf(float f) {
    unsigned x = __float_as_uint(f);
    return (short)((x + 0x7fffu + ((x >> 16) & 1u)) >> 16); // RNE
}
__device__ __forceinline__ unsigned pkbf(float lo, float hi) {
    unsigned r;
    asm("v_cvt_pk_bf16_f32 %0, %1, %2" : "=v"(r) : "v"(lo), "v"(hi));
    return r;
}

// ---------------------------------------------------------------------------
// Precompute: pexp = masked bf16 exp(pred), in chain-lane-sequential layout.
// byte addr = ((blk*1024 + row)*4 + c)*1024 + lane*16, each 16B = u32[4]:
//   w = 0,1 -> T = 2c, r-pairs (0,1),(2,3); w = 2,3 -> T = 2c+1.
// state s = 16*T + 4*l4 + r;  zero when row >= seq_len[b] or s >= 126.
// ---------------------------------------------------------------------------
__global__ __launch_bounds__(256)
void crf_pexp(const float* __restrict__ pred, const int* __restrict__ seq_len,
              unsigned short* __restrict__ pexp)
{
    int gid  = blockIdx.x * 256 + threadIdx.x;  // 8*1024*4*64 = 2,097,152
    int lane = gid & 63;
    int c    = (gid >> 6) & 3;
    int row  = (gid >> 8) & 1023;
    int blk  = gid >> 18;
    int l15 = lane & 15, l4 = lane >> 4;
    int b = blk * 16 + l15;
    bool live = row < seq_len[b];

    const float* src = pred + ((size_t)b * TDIM + row) * L + 32 * c + 4 * l4;
    f32x4 v0 = *(const f32x4*)(src);        // T = 2c,   states 32c+4l4+r
    f32x4 v1 = *(const f32x4*)(src + 16);   // T = 2c+1, states +16

    float e0[4], e1[4];
#pragma unroll
    for (int r = 0; r < 4; ++r) {
        int s0 = 32 * c + 4 * l4 + r;
        int s1 = s0 + 16;
        e0[r] = (live && s0 < 126) ? __expf(v0[r]) : 0.0f;
        e1[r] = (live && s1 < 126) ? __expf(v1[r]) : 0.0f;
    }
    i32x4 out;
    out[0] = (int)pkbf(e0[0], e0[1]);
    out[1] = (int)pkbf(e0[2], e0[3]);
    out[2] = (int)pkbf(e1[0], e1[1]);
    out[3] = (int)pkbf(e1[2], e1[3]);
    *(i32x4*)((char*)pexp + (size_t)gid * 16) = out;
}

// ---------------------------------------------------------------------------
// Chain: one wave per 16 batches. No LDS, no barriers, no shuffles in the loop.
// A = E^T as MFMA A-frags (state-permuted k so D-regs feed B-frags in place).
// perm: k -> state s = 16*(k>>5) + 64*((k>>2)&1) + 4*((k>>3)&3) + (k&3)
// ---------------------------------------------------------------------------
struct PB { i32x4 c[4]; };   // one step's pexp chunk (4 x dwordx4 per lane)
struct PF { f32x4 q[8]; };   // fallback: raw pred row (8 x float4 per lane)

template<bool PEXP>
__global__ __launch_bounds__(64, 1)
void crf_chain(const float* __restrict__ pred,
               const float* __restrict__ trans,
               const int* __restrict__ seq_len,
               const unsigned short* __restrict__ pexp,
               float* __restrict__ fwd_out)
{
    const int lane = threadIdx.x;
    const int l15 = lane & 15, l4 = lane >> 4;
    const int blk = blockIdx.x;
    const int b   = blk * BSUB + l15;

    // --- A-frags (held forever): A[T][kt] elem e = exp(trans[s][16T + l15]),
    //     s = 16*kt + 64*(e>>2) + 4*l4 + (e&3)
    bf16x8 A[8][4];
#pragma unroll
    for (int T = 0; T < 8; ++T)
#pragma unroll
        for (int kt = 0; kt < 4; ++kt) {
            bf16x8 v;
#pragma unroll
            for (int e = 0; e < 8; ++e) {
                int s = 16 * kt + 64 * (e >> 2) + 4 * l4 + (e & 3);
                v[e] = f2bf(__expf(trans[s * L + 16 * T + l15]));
            }
            A[T][kt] = v;
        }

    const int srow1 = seq_len[b] + 1;   // extraction step for this lane's batch

    // tmax = max(seq_len)+1 over the wave's 16 batches (l4 copies are equal)
    int mx = srow1;
#pragma unroll
    for (int d = 1; d < 16; d <<= 1) mx = max(mx, __shfl_xor(mx, d));
    const int tmaxR = __builtin_amdgcn_readfirstlane((mx + 3) & ~3);

    // --- B_0: V_0[s] = (s == START). START=126 -> k=126 -> l4==3, B[3] elem 6.
    B4 B[4];
#pragma unroll
    for (int kt = 0; kt < 4; ++kt) B[kt].i = (i32x4){0, 0, 0, 0};
    if (l4 == 3) B[3].i[3] = 0x3F80;    // elem6 low half = bf16(1.0)

    float C = 0.0f;

    const char* pxb = (const char*)pexp + (size_t)blk * 1024 * 4096;
    const float* pfb = pred + (size_t)b * TDIM * L + 4 * l4;

    auto loadPB = [&](PB& p, int row) {
        const i32x4* s = (const i32x4*)(pxb + (size_t)row * 4096) + lane;
        p.c[0] = s[0]; p.c[1] = s[64]; p.c[2] = s[128]; p.c[3] = s[192];
    };
    auto loadPF = [&](PF& p, int row) {
        const f32x4* s = (const f32x4*)(pfb + (size_t)row * L);
#pragma unroll
        for (int T = 0; T < 8; ++T) p.q[T] = s[T * 4];
    };

    // One recurrence step. Consumes pbuf (holds emission row t-1), reissues it
    // with row (t-1+DEPTH) for use at step t+DEPTH.
    auto stepP = [&](int t, PB& pb) {
        f32x4 acc[8];
#pragma unroll
        for (int T = 0; T < 8; ++T) acc[T] = (f32x4){0.f, 0.f, 0.f, 0.f};
#pragma unroll
        for (int kt = 0; kt < 4; ++kt)
#pragma unroll
            for (int T = 0; T < 8; ++T)
                acc[T] = __builtin_amdgcn_mfma_f32_16x16x32_bf16(A[T][kt], B[kt].v, acc[T], 0, 0, 0);

        // extraction: D'[STOP][b] before P; STOP=127 -> T=7, l4=3, reg 3
        if (l4 == 3 && t == srow1)
            fwd_out[b] = __logf(acc[7][3]) + C;

        // u = D' * P_t
        float u[8][4];
#pragma unroll
        for (int T = 0; T < 8; ++T) {
            int c = T >> 1, h = (T & 1) * 2;
            unsigned w0 = (unsigned)pb.c[c][h + 0];
            unsigned w1 = (unsigned)pb.c[c][h + 1];
            u[T][0] = acc[T][0] * __uint_as_float(w0 << 16);
            u[T][1] = acc[T][1] * __uint_as_float(w0 & 0xffff0000u);
            u[T][2] = acc[T][2] * __uint_as_float(w1 << 16);
            u[T][3] = acc[T][3] * __uint_as_float(w1 & 0xffff0000u);
        }
        // reissue this buffer 4 rows ahead
        loadPB(pb, min(t + 3, TDIM - 1));

        // renorm trigger (wave-uniform)
        float m[8];
#pragma unroll
        for (int T = 0; T < 8; ++T)
            m[T] = fmaxf(fmaxf(u[T][0], u[T][1]), fmaxf(u[T][2], u[T][3]));
        float mx4 = fmaxf(fmaxf(fmaxf(m[0], m[1]), fmaxf(m[2], m[3])),
                          fmaxf(fmaxf(m[4], m[5]), fmaxf(m[6], m[7])));
        if (__ballot(mx4 > 0x1p80f)) {
#pragma unroll
            for (int T = 0; T < 8; ++T)
#pragma unroll
                for (int r = 0; r < 4; ++r) u[T][r] *= 0x1p-64f;
            C += 44.3614195558365f;
        }

        // pack -> next B (in-place, no cross-lane movement by construction)
#pragma unroll
        for (int kt = 0; kt < 4; ++kt) {
            B[kt].i[0] = (int)pkbf(u[kt][0], u[kt][1]);
            B[kt].i[1] = (int)pkbf(u[kt][2], u[kt][3]);
            B[kt].i[2] = (int)pkbf(u[kt + 4][0], u[kt + 4][1]);
            B[kt].i[3] = (int)pkbf(u[kt + 4][2], u[kt + 4][3]);
        }
    };

    auto stepF = [&](int t, PF& pf) {
        f32x4 acc[8];
#pragma unroll
        for (int T = 0; T < 8; ++T) acc[T] = (f32x4){0.f, 0.f, 0.f, 0.f};
#pragma unroll
        for (int kt = 0; kt < 4; ++kt)
#pragma unroll
            for (int T = 0; T < 8; ++T)
                acc[T] = __builtin_amdgcn_mfma_f32_16x16x32_bf16(A[T][kt], B[kt].v, acc[T], 0, 0, 0);

        if (l4 == 3 && t == srow1)
            fwd_out[b] = __logf(acc[7][3]) + C;

        const bool live = (t < srow1);
        float u[8][4];
#pragma unroll
        for (int T = 0; T < 8; ++T)
#pragma unroll
            for (int r = 0; r < 4; ++r) {
                bool dead = !live || (T == 7 && l4 == 3 && r >= 2); // s>=126
                u[T][r] = dead ? 0.0f : acc[T][r] * __expf(pf.q[T][r]);
            }
        loadPF(pf, min(t + 1, TDIM - 1));

        float m[8];
#pragma unroll
        for (int T = 0; T < 8; ++T)
            m[T] = fmaxf(fmaxf(u[T][0], u[T][1]), fmaxf(u[T][2], u[T][3]));
        float mx4 = fmaxf(fmaxf(fmaxf(m[0], m[1]), fmaxf(m[2], m[3])),
                          fmaxf(fmaxf(m[4], m[5]), fmaxf(m[6], m[7])));
        if (__ballot(mx4 > 0x1p80f)) {
#pragma unroll
            for (int T = 0; T < 8; ++T)
#pragma unroll
                for (int r = 0; r < 4; ++r) u[T][r] *= 0x1p-64f;
            C += 44.3614195558365f;
        }
#pragma unroll
        for (int kt = 0; kt < 4; ++kt) {
            B[kt].i[0] = (int)pkbf(u[kt][0], u[kt][1]);
            B[kt].i[1] = (int)pkbf(u[kt][2], u[kt][3]);
            B[kt].i[2] = (int)pkbf(u[kt + 4][0], u[kt + 4][1]);
            B[kt].i[3] = (int)pkbf(u[kt + 4][2], u[kt + 4][3]);
        }
    };

    if constexpr (PEXP) {
        PB pa, pb_, pc, pd;
        loadPB(pa, 0); loadPB(pb_, min(1, TDIM - 1));
        loadPB(pc, min(2, TDIM - 1)); loadPB(pd, min(3, TDIM - 1));
        for (int t0 = 0; t0 < tmaxR; t0 += 4) {
            stepP(t0 + 1, pa);
            stepP(t0 + 2, pb_);
            stepP(t0 + 3, pc);
            stepP(t0 + 4, pd);
        }
    } else {
        PF fa, fb;
        loadPF(fa, 0); loadPF(fb, min(1, TDIM - 1));
        for (int t0 = 0; t0 < tmaxR; t0 += 2) {
            stepF(t0 + 1, fa);
            stepF(t0 + 2, fb);
        }
    }
}

// ---------------------------------------------------------------------------
// Gold path score (unchanged, verified exact).
// ---------------------------------------------------------------------------
__global__ __launch_bounds__(256)
void crf_score(const float* __restrict__ pred,
               const float* __restrict__ trans,
               const int* __restrict__ tags,
               const int* __restrict__ seq_len,
               float* __restrict__ score_out)
{
    const int b = blockIdx.x;
    const int tid = threadIdx.x;
    const int sl = seq_len[b];
    const int* tg = tags + b * TDIM;

    float s = 0.0f;
    for (int t = tid; t < sl; t += 256) {
        int tag = tg[t];
        s += pred[((long)b * TDIM + t) * L + tag];
        int prev = (t == 0) ? START : tg[t - 1];
        s += trans[prev * L + tag];
    }
    if (tid == 0) s += trans[tg[sl - 1] * L + STOP];

    __shared__ float red[4];
#pragma unroll
    for (int d = 1; d < 64; d <<= 1) s += __shfl_xor(s, d);
    if ((tid & 63) == 0) red[tid >> 6] = s;
    __syncthreads();
    if (tid == 0) score_out[b] = (red[0] + red[1]) + (red[2] + red[3]);
}

__global__ __launch_bounds__(128)
void crf_combine(const float* __restrict__ fwd,
                 const float* __restrict__ real,
                 float* __restrict__ out)
{
    const int tid = threadIdx.x;
    float s = fwd[tid] - real[tid];
#pragma unroll
    for (int d = 1; d < 64; d <<= 1) s += __shfl_xor(s, d);
    __shared__ float red[2];
    if ((tid & 63) == 0) red[tid >> 6] = s;
    __syncthreads();
    if (tid == 0) out[0] = red[0] + red[1];
}

extern "C" void kernel_launch(void* const* d_in, const int* in_sizes, int n_in,
                              void* d_out, int out_size, void* d_ws, size_t ws_size,
                              hipStream_t stream)
{
    const float* pred    = (const float*)d_in[0];
    const float* trans   = (const float*)d_in[1];
    const int*   tags    = (const int*)d_in[2];
    const int*   seq_len = (const int*)d_in[3];

    float* ws   = (float*)d_ws;
    float* fwd  = ws;        // 128 floats
    float* real = ws + 128;  // 128 floats

    const size_t pexp_bytes = (size_t)NBLK * 1024 * 4096; // 33.5 MB
    if (ws_size >= 1024 + pexp_bytes) {
        unsigned short* pexp = (unsigned short*)((char*)d_ws + 1024);
        crf_pexp<<<8192, 256, 0, stream>>>(pred, seq_len, pexp);
        crf_chain<true><<<NBLK, 64, 0, stream>>>(pred, trans, seq_len, pexp, fwd);
    } else {
        crf_chain<false><<<NBLK, 64, 0, stream>>>(pred, trans, seq_len, nullptr, fwd);
    }
    crf_score  <<<NBATCH, 256, 0, stream>>>(pred, trans, tags, seq_len, real);
    crf_combine<<<1, 128, 0, stream>>>(fwd, real, (float*)d_out);
}